// Round 1
// baseline (152.867 us; speedup 1.0000x reference)
//
#include <hip/hip_runtime.h>
#include <math.h>

typedef short v4s __attribute__((ext_vector_type(4)));
typedef short v8s __attribute__((ext_vector_type(8)));
typedef float v4f __attribute__((ext_vector_type(4)));

#define L2E 1.4426950408889634f
#define INV_SCALE 0.08838834764831845f       // 1/sqrt(128)
#define SCL2 (INV_SCALE * L2E)               // folded scale for exp2

static __device__ __forceinline__ short f2bf(float x) {
    union { float f; unsigned u; } c; c.f = x;
    unsigned u = c.u;
    unsigned r = (u + 0x7fffu + ((u >> 16) & 1u)) >> 16;  // RNE
    return (short)r;
}

typedef __attribute__((address_space(3))) void lds_vt;
typedef __attribute__((address_space(1))) const void gl_vt;
static __device__ __forceinline__ void gload_lds16(const void* g, void* l) {
    // async global->LDS, 16B/lane; LDS dest = wave-uniform base + lane*16
    __builtin_amdgcn_global_load_lds((gl_vt*)g, (lds_vt*)l, 16, 0, 0);
}

// ---- P0 fused: gemm+ELU role (x<1024) | transpose/mask role (x>=1024) ----
// gemm role self-transposes its W half through LDS (no Wt dependency).
// VaT is written with per-row chunk-XOR swizzle: within each 64-aligned kv
// group, 16B chunk g of row d stored at position g^(d&7)  -> conflict-free
// ds_read_b128 B-frags in k_attn.
__global__ __launch_bounds__(256) void k_pre(const float* __restrict__ ctx,
                                             const float* __restrict__ qry,
                                             const float* __restrict__ Win,
                                             const float* __restrict__ Wmem,
                                             const int* __restrict__ qmask,
                                             short* __restrict__ Qa,
                                             short* __restrict__ Ka,
                                             short* __restrict__ VaT,
                                             float* __restrict__ maskadd) {
    __shared__ __align__(16) char sbuf[64 * 264 * 2];   // 33792 B (union)
    int x = blockIdx.x;
    int tid = threadIdx.x;
    if (x < 1024) {
        // ---------------- gemm role ----------------
        short* WtS = (short*)sbuf;                      // [64 f][264 k-pad]
        int msel = x & 255, isel = (x >> 8) & 1, nh = (x >> 9) & 1;
        const float* X = isel ? qry : ctx;
        const float* W = isel ? Wmem : Win;
        short* Y = isel ? Ka : Qa;
        // stage Wt half: f' 0..63 (f = nh*64+f'), all k
#pragma unroll 8
        for (int i = 0; i < 64; ++i) {
            int id = i * 256 + tid;
            int k = id >> 6, fp = id & 63;
            WtS[fp * 264 + k] = f2bf(W[k * 128 + nh * 64 + fp]);
        }
        __syncthreads();

        int w = tid >> 6, lane = tid & 63;
        int ln = lane & 15, qd = lane >> 4;
        int m0 = msel * 64 + w * 16;
        v4f zero = {0.f, 0.f, 0.f, 0.f};
        v4f o[4];
#pragma unroll
        for (int i = 0; i < 4; ++i) o[i] = zero;
#pragma unroll
        for (int kk = 0; kk < 8; ++kk) {
            const float* xp = X + (size_t)(m0 + ln) * 256 + kk * 32 + qd * 8;
            float4 x0 = *(const float4*)xp;
            float4 x1 = *(const float4*)(xp + 4);
            v8s a;
            a[0] = f2bf(x0.x); a[1] = f2bf(x0.y); a[2] = f2bf(x0.z); a[3] = f2bf(x0.w);
            a[4] = f2bf(x1.x); a[5] = f2bf(x1.y); a[6] = f2bf(x1.z); a[7] = f2bf(x1.w);
#pragma unroll
            for (int nt = 0; nt < 4; ++nt) {
                v8s bfr = *(const v8s*)(WtS + (nt * 16 + ln) * 264 + kk * 32 + qd * 8);
                o[nt] = __builtin_amdgcn_mfma_f32_16x16x32_bf16(a, bfr, o[nt], 0, 0, 0);
            }
        }
#pragma unroll
        for (int nt = 0; nt < 4; ++nt) {
#pragma unroll
            for (int r = 0; r < 4; ++r) {
                float v = o[nt][r];
                v = v > 0.f ? v : 0.01f * (__expf(v) - 1.f);
                Y[(size_t)(m0 + qd * 4 + r) * 128 + (nh * 4 + nt) * 16 + ln] = f2bf(v);
            }
        }
    } else {
        // ---------------- transpose role ----------------
        float (*tile)[65] = (float(*)[65])sbuf;         // 16640 B
        int t = x - 1024;
        int q0 = (t & 31) * 64, d0 = ((t >> 5) & 3) * 64, b = t >> 7;
        int c = tid & 63;
        int r4 = tid >> 6;
#pragma unroll
        for (int i = 0; i < 16; ++i) {
            int r = r4 + i * 4;
            tile[r][c] = qry[(size_t)(b * 2048 + q0 + r) * 256 + d0 + c];
        }
        __syncthreads();
        int g = c >> 3, j = c & 7;
#pragma unroll
        for (int i = 0; i < 16; ++i) {
            int d = r4 + i * 4;                          // (d0+d)&7 == d&7
            int cs = ((g ^ (d & 7)) << 3) | j;           // chunk-XOR swizzle
            VaT[(size_t)(b * 256 + d0 + d) * 2048 + q0 + cs] = f2bf(tile[c][d]);
        }
        if (d0 == 0 && tid < 64) {
            int qq = b * 2048 + q0 + tid;
            maskadd[qq] = (qmask[qq] > 0) ? 0.f : -__builtin_inff();
        }
    }
}

// ------------- flash attention: NSPLIT=1, 32-row c-tiles, direct out ------
// 512 blocks (b = blk&7 -> same-b blocks share one XCD's L2). Wave w owns
// kv rows w*16..+15 per 64-step for QK (K frags prefetched one step ahead
// into registers), and d-quarter w*64..+63 for PV (V staged wave-private,
// async, double-buffered). P double-buffered in LDS with chunk-XOR swizzle
// -> ONE raw s_barrier per step; counted s_waitcnt vmcnt(13) keeps the next
// step's 13 VMEM ops (8 stage + 4 K + 1 mask) in flight across the barrier.
__global__ __launch_bounds__(256, 2) void k_attn(const short* __restrict__ Qa,
                                                 const short* __restrict__ Ka,
                                                 const short* __restrict__ VaT,
                                                 const float* __restrict__ maskadd,
                                                 float* __restrict__ out) {
    __shared__ __align__(16) short VaS[2][256 * 64];    // 64 KB: [buf][d][64kv] swizzled
    __shared__ __align__(16) short PSb[2][32 * 64];     // 8 KB: [buf][c][kv] swizzled

    const int STEPS = 32;
    int blk = blockIdx.x;
    int b = blk & 7;
    int c0 = (blk >> 3) * 32;

    int tid = threadIdx.x;
    int w = tid >> 6, lane = tid & 63, ln = lane & 15, qd = lane >> 4;

    const short* qbase = Qa + (size_t)(b * 2048) * 128;
    const short* kbase = Ka + (size_t)(b * 2048 + w * 16 + ln) * 128 + qd * 8;
    const short* vbase = VaT + (size_t)(b * 256) * 2048;
    const float* mbase = maskadd + b * 2048 + w * 16 + qd * 4;

    // Q fragments for both c-tiles (B-operand layout), resident
    v8s qf[2][4];
#pragma unroll
    for (int ct = 0; ct < 2; ++ct) {
        const short* qp = qbase + (size_t)(c0 + ct * 16 + ln) * 128 + qd * 8;
#pragma unroll
        for (int kk = 0; kk < 4; ++kk) qf[ct][kk] = *(const v8s*)(qp + kk * 32);
    }

    v4f zero = {0.f, 0.f, 0.f, 0.f};
    v4f o[2][4];                            // [ct][dt]
#pragma unroll
    for (int i = 0; i < 2; ++i)
#pragma unroll
        for (int j = 0; j < 4; ++j) o[i][j] = zero;
    float lacc[2] = {0.f, 0.f};

    // stage own d-quarter of V tile for kv window q0s into buf (wave-private)
    auto stageV = [&](int q0s, int buf) {
        short* base = &VaS[buf][0] + w * 4096;   // rows w*64..+63 (shorts: 64*64)
#pragma unroll
        for (int j = 0; j < 8; ++j) {
            int U = (w * 8 + j) * 64 + lane;     // 16B unit index
            int d = U >> 3, cc = U & 7;
            gload_lds16(vbase + (size_t)d * 2048 + q0s + cc * 8,
                        base + j * 512);
        }
    };

    // ---- prologue: V/K/mask for step 0 (13 VMEM ops, same as a step) ----
    stageV(0, 0);
    v8s kfA[4], kfB[4];
    float4 mkA, mkB;
#pragma unroll
    for (int kk = 0; kk < 4; ++kk) kfA[kk] = *(const v8s*)(kbase + kk * 32);
    mkA = *(const float4*)(mbase);

#define ATT_STEP(IT, KFC, MKC, KFN, MKN) do {                                  \
    int q0 = (IT) * 64;                                                        \
    int pb = (IT) & 1;                                                         \
    int itn = ((IT) + 1) & (STEPS - 1);                                        \
    stageV(itn * 64, pb ^ 1);                                                  \
    {                                                                          \
        const short* kp = kbase + (size_t)itn * 8192;                          \
        _Pragma("unroll")                                                      \
        for (int kk = 0; kk < 4; ++kk) KFN[kk] = *(const v8s*)(kp + kk * 32);  \
        MKN = *(const float4*)(mbase + itn * 64);                              \
    }                                                                          \
    /* retire prev step's 13 (V tile + K regs ready); keep these 13 flying */  \
    asm volatile("s_waitcnt vmcnt(13)" ::: "memory");                          \
    short* PScur = &PSb[pb][0];                                                \
    int kvb = q0 + w * 16 + qd * 4;                                            \
    _Pragma("unroll")                                                          \
    for (int ct = 0; ct < 2; ++ct) {                                           \
        v4f s = zero;                                                          \
        _Pragma("unroll")                                                      \
        for (int kk = 0; kk < 4; ++kk)                                         \
            s = __builtin_amdgcn_mfma_f32_16x16x32_bf16(KFC[kk], qf[ct][kk],   \
                                                        s, 0, 0, 0);           \
        int cg = c0 + ct * 16 + ln;                                            \
        v4s pw;                                                                \
        float ls = 0.f;                                                        \
        _Pragma("unroll")                                                      \
        for (int r = 0; r < 4; ++r) {                                          \
            float v = s[r] * SCL2 + (&MKC.x)[r];                               \
            if (kvb + r == cg) v = -__builtin_inff();                          \
            float p = exp2f(v);                                                \
            ls += p;                                                           \
            pw[r] = f2bf(p);                                                   \
        }                                                                      \
        lacc[ct] += ls;                                                        \
        int hs = ((w * 2 + (qd >> 1)) ^ (ln & 7));                             \
        *(v4s*)(PScur + (ct * 16 + ln) * 64 + hs * 8 + (qd & 1) * 4) = pw;     \
    }                                                                          \
    asm volatile("s_waitcnt lgkmcnt(0)" ::: "memory");                         \
    __builtin_amdgcn_s_barrier();                                              \
    asm volatile("" ::: "memory");                                             \
    const short* vs = &VaS[pb][0];                                             \
    __builtin_amdgcn_s_setprio(1);                                             \
    _Pragma("unroll")                                                          \
    for (int kk2 = 0; kk2 < 2; ++kk2) {                                        \
        v8s pf[2], vf[4];                                                      \
        _Pragma("unroll")                                                      \
        for (int ct = 0; ct < 2; ++ct)                                         \
            pf[ct] = *(const v8s*)(PScur + (ct * 16 + ln) * 64 +               \
                                   (((kk2 * 4 + qd) ^ (ln & 7)) << 3));        \
        _Pragma("unroll")                                                      \
        for (int dt = 0; dt < 4; ++dt) {                                       \
            int d = w * 64 + dt * 16 + ln;                                     \
            vf[dt] = *(const v8s*)(vs + d * 64 +                               \
                                   (((kk2 * 4 + qd) ^ (ln & 7)) << 3));        \
        }                                                                      \
        _Pragma("unroll")                                                      \
        for (int ct = 0; ct < 2; ++ct)                                         \
            _Pragma("unroll")                                                  \
            for (int dt = 0; dt < 4; ++dt)                                     \
                o[ct][dt] = __builtin_amdgcn_mfma_f32_16x16x32_bf16(           \
                    pf[ct], vf[dt], o[ct][dt], 0, 0, 0);                       \
    }                                                                          \
    __builtin_amdgcn_s_setprio(0);                                             \
} while (0)

#pragma unroll 1
    for (int it2 = 0; it2 < STEPS; it2 += 2) {
        ATT_STEP(it2, kfA, mkA, kfB, mkB);
        ATT_STEP(it2 + 1, kfB, mkB, kfA, mkA);
    }
#undef ATT_STEP

    // ---- l: reduce over qd in-wave, over waves via LDS (PS space reused) --
    __syncthreads();
    float* lS = (float*)&PSb[0][0];
#pragma unroll
    for (int ct = 0; ct < 2; ++ct) {
        float v = lacc[ct];
        v += __shfl_xor(v, 16);
        v += __shfl_xor(v, 32);
        if (qd == 0) lS[w * 32 + ct * 16 + ln] = v;
    }
    __syncthreads();

#pragma unroll
    for (int ct = 0; ct < 2; ++ct) {
        float4 l0 = *(const float4*)(lS + 0 * 32 + ct * 16 + qd * 4);
        float4 l1 = *(const float4*)(lS + 1 * 32 + ct * 16 + qd * 4);
        float4 l2 = *(const float4*)(lS + 2 * 32 + ct * 16 + qd * 4);
        float4 l3 = *(const float4*)(lS + 3 * 32 + ct * 16 + qd * 4);
        int rowg = b * 2048 + c0 + ct * 16 + qd * 4;
#pragma unroll
        for (int r = 0; r < 4; ++r) {
            float lv = (&l0.x)[r] + (&l1.x)[r] + (&l2.x)[r] + (&l3.x)[r];
            float inv = 1.f / lv;
#pragma unroll
            for (int dt = 0; dt < 4; ++dt)
                out[(size_t)(rowg + r) * 256 + w * 64 + dt * 16 + ln] =
                    o[ct][dt][r] * inv;
        }
    }
}

extern "C" void kernel_launch(void* const* d_in, const int* in_sizes, int n_in,
                              void* d_out, int out_size, void* d_ws, size_t ws_size,
                              hipStream_t stream) {
    const float* ctx  = (const float*)d_in[0];
    const float* qry  = (const float*)d_in[1];
    const float* win  = (const float*)d_in[2];
    const float* wmem = (const float*)d_in[3];
    const int* qmask  = (const int*)d_in[4];
    float* out = (float*)d_out;

    char* ws = (char*)d_ws;
    short* Qa      = (short*)(ws);                          // 4 MB
    short* Ka      = (short*)(ws + (4u << 20));             // 4 MB
    short* VaT     = (short*)(ws + (8u << 20));             // 8 MB
    float* maskadd = (float*)(ws + (16u << 20));            // 64 KB

    k_pre<<<dim3(2048), 256, 0, stream>>>(ctx, qry, win, wmem, qmask,
                                          Qa, Ka, VaT, maskadd);
    k_attn<<<dim3(512), 256, 0, stream>>>(Qa, Ka, VaT, maskadd, out);
}